// Round 8
// baseline (260.353 us; speedup 1.0000x reference)
//
#include <hip/hip_runtime.h>
#include <stdint.h>

#define NBINS 32
#define NBATCH 64
#define NPB (512 * 512)            // pixels per batch
#define BPB 32                     // blocks per batch
#define TPB 256
#define EPB (NPB / BPB)            // 8192 elems per block
#define NT 8                       // tiles (iterations) per block

// ws layout (uint32 words):
#define WS_PRED 2048
#define WS_NM   4096
#define WS_FLAG 4160
#define WS_WORDS 4161

// global_load_lds: gfx950 async global->LDS DMA. dest = wave-uniform base +
// lane*size (linear), source is per-lane.
#define GLDS16(gp, lp)                                              \
  __builtin_amdgcn_global_load_lds(                                 \
      (__attribute__((address_space(1))) void*)(gp),                \
      (__attribute__((address_space(3))) void*)(lp), 16, 0, 0)
#define GLDS4(gp, lp)                                               \
  __builtin_amdgcn_global_load_lds(                                 \
      (__attribute__((address_space(1))) void*)(gp),                \
      (__attribute__((address_space(3))) void*)(lp), 4, 0, 0)

__global__ void detect_mask_kernel(const uint32_t* __restrict__ mw,
                                   uint32_t* __restrict__ flag) {
  uint32_t v = mw[threadIdx.x];
  if (__any(v > 1u) && threadIdx.x == 0) *flag = 1u;
}

// Exact searchsorted(edges, x, 'right')-1 for edges = linspace(-3,3,33):
// every true edge is an exact multiple of 0.1875f (=3/16). Out-of-range or
// masked (folded to 1e2f) values land outside [0,31].
__device__ __forceinline__ int bin_of(float x) {
  if (x == 3.0f) return NBINS - 1;  // x == last edge -> last bin (closed)
  float t = __builtin_fmaf(x, 5.333333492279053f, 16.0f);  // (x+3)*32/6
  int i = (int)t;
  float fi = (float)i;
  float elo = __builtin_fmaf(fi, 0.1875f, -3.0f);
  float ehi = elo + 0.1875f;
  i += (x >= ehi) ? 1 : 0;
  i -= (x < elo) ? 1 : 0;
  return i;
}

__device__ __forceinline__ void bin4(const float4 x, uint32_t w,
                                     uint32_t* __restrict__ h) {
  const float a0 = (w & 0x000000ffu) ? x.x : 1e2f;
  const float a1 = (w & 0x0000ff00u) ? x.y : 1e2f;
  const float a2 = (w & 0x00ff0000u) ? x.z : 1e2f;
  const float a3 = (w & 0xff000000u) ? x.w : 1e2f;
  int i0 = bin_of(a0), i1 = bin_of(a1), i2 = bin_of(a2), i3 = bin_of(a3);
  if ((unsigned)i0 < 32u) atomicAdd(&h[i0], 1u);
  if ((unsigned)i1 < 32u) atomicAdd(&h[i1], 1u);
  if ((unsigned)i2 < 32u) atomicAdd(&h[i2], 1u);
  if ((unsigned)i3 < 32u) atomicAdd(&h[i3], 1u);
}

__device__ __forceinline__ void hist_epilogue(uint32_t nm, uint32_t* h_obs,
                                              uint32_t* h_pred, int b,
                                              uint32_t* ws, int tid) {
#pragma unroll
  for (int off = 32; off >= 1; off >>= 1) nm += __shfl_down(nm, off);
  if ((tid & 63) == 0) atomicAdd(&ws[WS_NM + b], nm);
  __syncthreads();
  if (tid < 2 * NBINS) {
    const uint32_t v = (tid < NBINS) ? h_obs[tid] : h_pred[tid - NBINS];
    if (v)
      atomicAdd(&ws[(tid < NBINS ? 0 : WS_PRED) + b * NBINS + (tid & 31)], v);
  }
}

// ---------------- A: control — R2 structure (rolled demand loads) ----------
__global__ __launch_bounds__(TPB) void hist_a(
    const float* __restrict__ obs, const float* __restrict__ pred,
    const void* __restrict__ mask, uint32_t* __restrict__ ws) {
  __shared__ uint32_t h_obs[NBINS], h_pred[NBINS];
  const int tid = threadIdx.x;
  if (tid < NBINS) { h_obs[tid] = 0u; h_pred[tid] = 0u; }
  __syncthreads();

  const uint32_t is_u8 = ws[WS_FLAG];
  const int b = (int)blockIdx.x / BPB;          // 0..31
  const int chunk = (int)blockIdx.x % BPB;
  const size_t base_f4 = ((size_t)b * NPB + (size_t)chunk * EPB) >> 2;

  const float4* __restrict__ o4 = (const float4*)obs;
  const float4* __restrict__ p4 = (const float4*)pred;
  const uint32_t* __restrict__ mwp = (const uint32_t*)mask;
  const int4* __restrict__ mip = (const int4*)mask;

  uint32_t nm = 0;
  for (int it = 0; it < NT; ++it) {
    const size_t idx = base_f4 + (size_t)(it * TPB) + tid;
    const float4 xo = o4[idx];
    const float4 xp = p4[idx];
    uint32_t w;
    if (is_u8) {
      w = mwp[idx];
      nm += (w & 0xffu) + ((w >> 8) & 0xffu) + ((w >> 16) & 0xffu) + (w >> 24);
    } else {
      const int4 mv = mip[idx];
      w = (mv.x ? 0xffu : 0u) | (mv.y ? 0xff00u : 0u) |
          (mv.z ? 0xff0000u : 0u) | (mv.w ? 0xff000000u : 0u);
      nm += (mv.x ? 1u : 0u) + (mv.y ? 1u : 0u) + (mv.z ? 1u : 0u) +
            (mv.w ? 1u : 0u);
    }
    bin4(xo, w, h_obs);
    bin4(xp, w, h_pred);
  }
  hist_epilogue(nm, h_obs, h_pred, b, ws, tid);
}

// ---------------- B: experiment — global_load_lds DMA pipeline -------------
// Wave-private double-buffered staging; counted vmcnt, no in-loop barriers.
__global__ __launch_bounds__(TPB) void hist_b(
    const float* __restrict__ obs, const float* __restrict__ pred,
    const void* __restrict__ mask, uint32_t* __restrict__ ws) {
  // per wave, per buf: obs 1024B | pred 1024B | mask 256B = 2304B
  __shared__ __align__(16) uint8_t stage[4][2][2304];
  __shared__ uint32_t h_obs[NBINS], h_pred[NBINS];
  const int tid = threadIdx.x;
  const int wv = tid >> 6, ln = tid & 63;
  if (tid < NBINS) { h_obs[tid] = 0u; h_pred[tid] = 0u; }
  __syncthreads();  // before any DMA issue (barrier drains vmcnt once, here)

  const uint32_t is_u8 = ws[WS_FLAG];
  const int b = 32 + (int)blockIdx.x / BPB;     // 32..63
  const int chunk = (int)blockIdx.x % BPB;
  const size_t base_f4 = ((size_t)b * NPB + (size_t)chunk * EPB) >> 2;

  const float4* __restrict__ o4 = (const float4*)obs;
  const float4* __restrict__ p4 = (const float4*)pred;
  const uint32_t* __restrict__ mwp = (const uint32_t*)mask;
  const int4* __restrict__ mip = (const int4*)mask;

  uint32_t nm = 0;

  if (is_u8) {
    // lane's global index (float4 / mask-dword units); tile stride = 256
    const size_t wbase = base_f4 + (size_t)(wv * 64) + ln;
    uint8_t* const s0 = &stage[wv][0][0];
    uint8_t* const s1 = &stage[wv][1][0];

    // prologue: tile 0 -> buf 0 (3 DMA ops in flight)
    GLDS16(o4 + wbase, s0);
    GLDS16(p4 + wbase, s0 + 1024);
    GLDS4(mwp + wbase, s0 + 2048);

#pragma unroll
    for (int t = 0; t < NT; ++t) {
      uint8_t* const cur = (t & 1) ? s1 : s0;
      uint8_t* const nxt = (t & 1) ? s0 : s1;
      if (t + 1 < NT) {
        const size_t ni = wbase + (size_t)((t + 1) * 256);
        GLDS16(o4 + ni, nxt);
        GLDS16(p4 + ni, nxt + 1024);
        GLDS4(mwp + ni, nxt + 2048);
        // tile t's 3 DMAs are the 3 oldest of 6 outstanding
        asm volatile("s_waitcnt vmcnt(3)" ::: "memory");
      } else {
        asm volatile("s_waitcnt vmcnt(0)" ::: "memory");
      }
      __builtin_amdgcn_sched_barrier(0);

      const uint32_t w = *(const uint32_t*)(cur + 2048 + ln * 4);
      const float4 xo = *(const float4*)(cur + ln * 16);
      const float4 xp = *(const float4*)(cur + 1024 + ln * 16);
      nm += (w & 0xffu) + ((w >> 8) & 0xffu) + ((w >> 16) & 0xffu) + (w >> 24);
      bin4(xo, w, h_obs);
      bin4(xp, w, h_pred);
    }
  } else {
    // int32-mask fallback: plain rolled demand loads (A-style)
    for (int it = 0; it < NT; ++it) {
      const size_t idx = base_f4 + (size_t)(it * TPB) + tid;
      const float4 xo = o4[idx];
      const float4 xp = p4[idx];
      const int4 mv = mip[idx];
      const uint32_t w = (mv.x ? 0xffu : 0u) | (mv.y ? 0xff00u : 0u) |
                         (mv.z ? 0xff0000u : 0u) | (mv.w ? 0xff000000u : 0u);
      nm += (mv.x ? 1u : 0u) + (mv.y ? 1u : 0u) + (mv.z ? 1u : 0u) +
            (mv.w ? 1u : 0u);
      bin4(xo, w, h_obs);
      bin4(xp, w, h_pred);
    }
  }
  hist_epilogue(nm, h_obs, h_pred, b, ws, tid);
}

__global__ __launch_bounds__(64) void finalize_kernel(
    const uint32_t* __restrict__ ws, const float* __restrict__ edges,
    float* __restrict__ out) {
  __shared__ float pobs[NBATCH][NBINS + 1];
  __shared__ float ppred[NBATCH][NBINS + 1];
  __shared__ float w_sh[NBINS];
  __shared__ float bw_sh[NBINS];
  __shared__ float w_scale;

  const int t = threadIdx.x;

  const uint32_t* co = ws + t * NBINS;
  const uint32_t* cp = ws + WS_PRED + t * NBINS;
  const uint32_t nmask = ws[WS_NM + t];

  float sum_o = 0.0f, sum_p = 0.0f;
#pragma unroll
  for (int j = 0; j < NBINS; ++j) {
    float vo = (nmask == 0u) ? 1.0f : (float)co[j];
    float vp = (nmask == 0u) ? 1.0f : (float)cp[j];
    pobs[t][j] = vo;  sum_o += vo;
    ppred[t][j] = vp; sum_p += vp;
  }
  const float inv_to = 1.0f / fmaxf(sum_o, 1.0f);
  const float inv_tp = 1.0f / fmaxf(sum_p, 1.0f);
#pragma unroll
  for (int j = 0; j < NBINS; ++j) {
    pobs[t][j] *= inv_to;
    ppred[t][j] = 0.95f * (ppred[t][j] * inv_tp) + 0.05f / (float)NBINS;
  }
  __syncthreads();

  if (t < NBINS) {
    float s = 0.0f;
#pragma unroll
    for (int b = 0; b < NBATCH; ++b) s += pobs[b][t];
    const float avg = s / (float)NBATCH;
    w_sh[t] = 1.0f / (avg + 1e-3f);
    const int j2 = (t < NBINS - 1) ? t : (NBINS - 2);
    const float mA = 0.5f * (edges[j2] + edges[j2 + 1]);
    const float mB = 0.5f * (edges[j2 + 1] + edges[j2 + 2]);
    bw_sh[t] = mB - mA;
  }
  __syncthreads();
  if (t == 0) {
    float sw = 0.0f;
#pragma unroll
    for (int j = 0; j < NBINS; ++j) sw += w_sh[j];
    w_scale = (float)NBINS / sw;
  }
  __syncthreads();

  float ce = 0.0f, w2 = 0.0f, cdf_o = 0.0f, cdf_p = 0.0f;
#pragma unroll
  for (int j = 0; j < NBINS; ++j) {
    const float po = pobs[t][j];
    const float pp = ppred[t][j];
    ce += -po * logf(pp + 1e-8f) * (w_sh[j] * w_scale);
    cdf_o += po;
    cdf_p += pp;
    const float dd = cdf_o - cdf_p;
    w2 += dd * dd * bw_sh[j];
  }

  float ce_r = ce, w2_r = w2;
#pragma unroll
  for (int off = 32; off >= 1; off >>= 1) {
    ce_r += __shfl_down(ce_r, off);
    w2_r += __shfl_down(w2_r, off);
  }
  if (t == 0) {
    const float ce_m = ce_r / (float)NBATCH;
    const float w2_m = w2_r / (float)NBATCH;
    out[0] = (ce_m + 0.1f * w2_m) / (float)NBINS;
    out[1] = ce_m;
    out[2] = w2_m;
  }

#pragma unroll
  for (int j = 0; j < NBINS; ++j) {
    out[3 + t * NBINS + j] = pobs[t][j];
    out[3 + NBATCH * NBINS + t * NBINS + j] = ppred[t][j];
  }
}

extern "C" void kernel_launch(void* const* d_in, const int* in_sizes, int n_in,
                              void* d_out, int out_size, void* d_ws,
                              size_t ws_size, hipStream_t stream) {
  const float* obs = (const float*)d_in[0];
  const float* pred = (const float*)d_in[1];
  const void* mask = d_in[2];
  const float* edges = (const float*)d_in[3];
  float* out = (float*)d_out;
  uint32_t* ws = (uint32_t*)d_ws;

  hipMemsetAsync(d_ws, 0, WS_WORDS * sizeof(uint32_t), stream);
  detect_mask_kernel<<<1, 64, 0, stream>>>((const uint32_t*)mask,
                                           ws + WS_FLAG);
  hist_a<<<32 * BPB, TPB, 0, stream>>>(obs, pred, mask, ws);   // batches 0-31
  hist_b<<<32 * BPB, TPB, 0, stream>>>(obs, pred, mask, ws);   // batches 32-63
  finalize_kernel<<<1, 64, 0, stream>>>(ws, edges, out);
}